// Round 16
// baseline (702.786 us; speedup 1.0000x reference)
//
#include <hip/hip_runtime.h>
#include <hip/hip_bf16.h>
#include <type_traits>

typedef __hip_bfloat16 bf16;
typedef __attribute__((ext_vector_type(8))) short bf16x8;
typedef __attribute__((ext_vector_type(4))) float f32x4;

// ---------- helpers ----------
__device__ __forceinline__ float LD(const float* p){ return *p; }
__device__ __forceinline__ float LD(const bf16* p){ return __bfloat162float(*p); }
__device__ __forceinline__ void ST(float* p, float v){ *p = v; }
__device__ __forceinline__ void ST(bf16* p, float v){ *p = __float2bfloat16(v); }
__device__ __forceinline__ float sigm(float v){ return 1.f/(1.f + expf(-v)); }
__device__ __forceinline__ ushort f2b(float f){            // RNE f32->bf16 bits
    unsigned u = __float_as_uint(f);
    return (ushort)((u + 0x7fffu + ((u>>16)&1u)) >> 16);
}

#define NEPS 1e-5f

// ---------- dwconv tile staging: 66x66 padded tile from a 64x64 plane ----------
__device__ __forceinline__ void stage_tile(const float* __restrict__ xp, float* tile, int tid){
    for (int i = tid; i < 66*66; i += 256) {
        int r = i/66, c = i%66;
        int gr = r-1, gc = c-1;
        float val = 0.f;
        if (gr >= 0 && gr < 64 && gc >= 0 && gc < 64) val = xp[gr*64+gc];
        tile[i] = val;
    }
}
__device__ __forceinline__ void stage_tile(const bf16* __restrict__ xp, float* tile, int tid){
    for (int i = tid; i < 2048; i += 256) {
        int r = i >> 5, c = (i & 31) << 1;
        uint u = *(const uint*)((const ushort*)xp + r*64 + c);
        tile[(r+1)*66 + c+1] = __uint_as_float(u << 16);
        tile[(r+1)*66 + c+2] = __uint_as_float(u & 0xffff0000u);
    }
    for (int i = tid; i < 260; i += 256) {
        int tr, tc;
        if (i < 66)       { tr = 0;      tc = i; }
        else if (i < 132) { tr = 65;     tc = i-66; }
        else if (i < 196) { tr = i-131;  tc = 0; }
        else              { tr = i-195;  tc = 65; }
        tile[tr*66 + tc] = 0.f;
    }
}
__device__ __forceinline__ void st_pair(float* op, int idx, float a, float b){
    op[idx] = a; op[idx+1] = b;
}
__device__ __forceinline__ void st_pair(bf16* op, int idx, float a, float b){
    uint u = (uint)f2b(a) | ((uint)f2b(b)<<16);
    *(uint*)((ushort*)op + idx) = u;
}

// ---------- depthwise 3x3 + BN + alpha blend (one block per (b,ch) plane) ----------
template<typename TIN, typename TOUT>
__global__ __launch_bounds__(256) void dwconv_bn_blend(
        const TIN* __restrict__ xin, TOUT* __restrict__ xout,
        const float* __restrict__ w, const float* __restrict__ gg, const float* __restrict__ bb,
        const float* __restrict__ mm, const float* __restrict__ vv,
        const float* __restrict__ alpha, int arow)
{
    __shared__ float tile[66*66];
    int blk = blockIdx.x;
    int ch = blk & 255;
    const TIN* xp = xin + (size_t)blk*4096;
    TOUT* op = xout + (size_t)blk*4096;
    int tid = threadIdx.x;
    stage_tile(xp, tile, tid);
    __syncthreads();
    float wv[9];
    #pragma unroll
    for (int k=0;k<9;k++) wv[k] = w[ch*9+k];
    float sc = gg[ch] * rsqrtf(vv[ch] + NEPS);
    float mv = mm[ch], bv = bb[ch];
    float av = sigm(alpha[arow*256+ch]);
    for (int p2 = tid; p2 < 2048; p2 += 256) {
        int r = p2 >> 5, c = (p2 & 31) << 1;
        float a0 = 0.f, a1 = 0.f;
        #pragma unroll
        for (int dr=0;dr<3;dr++)
            #pragma unroll
            for (int dc=0;dc<3;dc++){
                float wk = wv[dr*3+dc];
                a0 += wk*tile[(r+dr)*66 + c+dc];
                a1 += wk*tile[(r+dr)*66 + c+1+dc];
            }
        float bn0 = (a0 - mv)*sc + bv;
        float bn1 = (a1 - mv)*sc + bv;
        float xv0 = tile[(r+1)*66 + c+1];
        float xv1 = tile[(r+1)*66 + c+2];
        st_pair(op, r*64+c, (1.f-av)*xv0 + av*bn0, (1.f-av)*xv1 + av*bn1);
    }
}

// ---------- LayerNorm stats (f32 path) ----------
__global__ __launch_bounds__(256) void ln_stats_f(const float* __restrict__ x1,
        float* __restrict__ meanp, float* __restrict__ invp)
{
    int blk = blockIdx.x;
    int b = blk >> 4;
    int l = ((blk & 15) << 8) + threadIdx.x;
    const float* xp = x1 + (size_t)b*256*4096 + l;
    float mean = 0.f, m2 = 0.f;
    for (int c=0;c<256;c++){ float v = xp[(size_t)c*4096]; mean += v; m2 += v*v; }
    mean *= (1.f/256.f); m2 *= (1.f/256.f);
    meanp[b*4096 + l] = mean;
    invp[b*4096 + l] = rsqrtf(m2 - mean*mean + NEPS);
}

// ---------- LayerNorm stats (bf16 path, 2 columns/thread via uint loads) ----------
__global__ __launch_bounds__(256) void ln_stats_bf(const bf16* __restrict__ x1,
        float* __restrict__ meanp, float* __restrict__ invp)
{
    int blk = blockIdx.x;
    int b = blk >> 3;
    int l = ((blk & 7) << 9) + (threadIdx.x << 1);
    const ushort* xp = (const ushort*)x1 + (size_t)b*256*4096 + l;
    float mean0 = 0.f, m20 = 0.f, mean1 = 0.f, m21 = 0.f;
    for (int c=0;c<256;c++){
        uint u = *(const uint*)&xp[(size_t)c*4096];
        float v0 = __uint_as_float(u << 16);
        float v1 = __uint_as_float(u & 0xffff0000u);
        mean0 += v0; m20 += v0*v0;
        mean1 += v1; m21 += v1*v1;
    }
    mean0 *= (1.f/256.f); m20 *= (1.f/256.f);
    mean1 *= (1.f/256.f); m21 *= (1.f/256.f);
    meanp[b*4096 + l]   = mean0;
    meanp[b*4096 + l+1] = mean1;
    invp[b*4096 + l]   = rsqrtf(m20 - mean0*mean0 + NEPS);
    invp[b*4096 + l+1] = rsqrtf(m21 - mean1*mean1 + NEPS);
}

// ---------- prep: weights->bf16, fold BN ----------
__global__ __launch_bounds__(256) void prep_k(
        const float* __restrict__ f1w, const float* __restrict__ f2w,
        const float* __restrict__ bcdtw,
        const float* __restrict__ g1, const float* __restrict__ b1,
        const float* __restrict__ m1, const float* __restrict__ v1,
        const float* __restrict__ g2, const float* __restrict__ b2,
        const float* __restrict__ m2, const float* __restrict__ v2,
        ushort* __restrict__ w1bf, ushort* __restrict__ w2bf,
        ushort* __restrict__ wbc,
        float* __restrict__ sc1, float* __restrict__ sb1,
        float* __restrict__ sc2, float* __restrict__ sb2)
{
    int i = blockIdx.x*256 + threadIdx.x;
    if (i < 262144) {
        w1bf[i] = f2b(f1w[i]);
        w2bf[i] = f2b(f2w[i]);
    }
    if (i < 49152) wbc[i] = f2b(bcdtw[i]);
    if (i < 1024) { float s = g1[i]*rsqrtf(v1[i]+NEPS); sc1[i]=s; sb1[i]=b1[i]-m1[i]*s; }
    if (i < 256)  { float s = g2[i]*rsqrtf(v2[i]+NEPS); sc2[i]=s; sb2[i]=b2[i]-m2[i]*s; }
}

// ---------- bc_dt = bcdt_w(192,256) @ LN(x1), MFMA; side-writes xn_bf ----------
template<typename TX>
__global__ __launch_bounds__(256) void bcdt_mfma(
        const TX* __restrict__ x1,
        const float* __restrict__ meanp, const float* __restrict__ invp,
        const float* __restrict__ lnw, const float* __restrict__ lnb,
        const ushort* __restrict__ wbc,      // [192][256] bf16
        bf16* __restrict__ bc, ushort* __restrict__ xn_bf, int b0)
{
    __shared__ __align__(16) ushort Xs[64*256];  // [px][c] bf16, 16B-block XOR swizzle
    int blk = blockIdx.x;
    int lb = blk >> 6;
    int b  = b0 + lb;
    int l0 = (blk & 63) << 6;
    int tid = threadIdx.x, lane = tid & 63, w = tid >> 6;
    const TX* xp = x1 + (size_t)b*256*4096 + l0;
    float mval = meanp[b*4096 + l0 + lane];
    float ival = invp [b*4096 + l0 + lane];
    ushort* xnp = xn_bf + (size_t)lb*256*4096 + l0;

    for (int cc = w*8; cc < 256; cc += 32) {
        ushort u[8];
        #pragma unroll
        for (int j=0;j<8;j++){
            float v = LD(&xp[(size_t)(cc+j)*4096 + lane]);
            float xn = (v - mval)*ival*lnw[cc+j] + lnb[cc+j];
            u[j] = f2b(xn);
            xnp[(size_t)(cc+j)*4096 + lane] = u[j];
        }
        uint4 pk;
        pk.x = (uint)u[0] | ((uint)u[1]<<16);
        pk.y = (uint)u[2] | ((uint)u[3]<<16);
        pk.z = (uint)u[4] | ((uint)u[5]<<16);
        pk.w = (uint)u[6] | ((uint)u[7]<<16);
        int g = (cc>>3) ^ (lane&7);
        *(uint4*)&Xs[lane*256 + g*8] = pk;
    }
    __syncthreads();

    f32x4 zero4 = {0.f,0.f,0.f,0.f};
    f32x4 acc[3][4];
    #pragma unroll
    for (int m=0;m<3;m++)
        #pragma unroll
        for (int f=0;f<4;f++) acc[m][f] = zero4;

    int hbase = w*48;
    #pragma unroll
    for (int ks=0; ks<8; ks++){
        bf16x8 afr[3];
        #pragma unroll
        for (int m=0;m<3;m++)
            afr[m] = *(const bf16x8*)&wbc[(size_t)(hbase + m*16 + (lane&15))*256
                                          + ks*32 + (lane>>4)*8];
        #pragma unroll
        for (int f=0;f<4;f++){
            int px = f*16 + (lane&15);
            int g = (ks*4 + (lane>>4)) ^ (px&7);
            bf16x8 bfr = *(const bf16x8*)&Xs[px*256 + g*8];
            #pragma unroll
            for (int m=0;m<3;m++)
                acc[m][f] = __builtin_amdgcn_mfma_f32_16x16x32_bf16(afr[m], bfr, acc[m][f], 0,0,0);
        }
    }
    bf16* op = bc + (size_t)lb*192*4096 + l0;
    #pragma unroll
    for (int m=0;m<3;m++)
        #pragma unroll
        for (int r=0;r<4;r++){
            int o = hbase + m*16 + (lane>>4)*4 + r;
            #pragma unroll
            for (int f=0;f<4;f++){
                int px = f*16 + (lane&15);
                op[(size_t)o*4096 + px] = __float2bfloat16(acc[m][f][r]);
            }
        }
}

// ---------- plain depthwise 3x3, in-place (192 channels per batch), bf16 ----------
__global__ __launch_bounds__(256) void dwconv_plain(bf16* __restrict__ data, const float* __restrict__ w)
{
    __shared__ float tile[66*66];
    int blk = blockIdx.x;
    int ch = blk % 192;
    bf16* xp = data + (size_t)blk*4096;
    int tid = threadIdx.x;
    stage_tile(xp, tile, tid);
    __syncthreads();
    float wv[9];
    #pragma unroll
    for (int k=0;k<9;k++) wv[k] = w[ch*9+k];
    for (int p2 = tid; p2 < 2048; p2 += 256) {
        int r = p2 >> 5, c = (p2 & 31) << 1;
        float a0 = 0.f, a1 = 0.f;
        #pragma unroll
        for (int dr=0;dr<3;dr++)
            #pragma unroll
            for (int dc=0;dc<3;dc++){
                float wk = wv[dr*3+dc];
                a0 += wk*tile[(r+dr)*66 + c+dc];
                a1 += wk*tile[(r+dr)*66 + c+1+dc];
            }
        st_pair(xp, r*64+c, a0, a1);
    }
}

// ---------- softmax over L (per (lb,s)) and AB = Am*Bm in place over Bm rows ----------
__global__ __launch_bounds__(256) void softmax_ab(bf16* __restrict__ bc, const float* __restrict__ A)
{
    __shared__ float red[8];
    int blk = blockIdx.x;
    int lb = blk >> 6;
    int s = blk & 63;
    bf16* dtp = bc + ((size_t)lb*192 + 128 + s)*4096;
    bf16* bmp = bc + ((size_t)lb*192 + s)*4096;
    int tid = threadIdx.x;
    float Av = A[s];
    float vals[16];
    float mx = -1e30f;
    #pragma unroll
    for (int i=0;i<16;i++){ vals[i] = LD(&dtp[i*256+tid]) + Av; mx = fmaxf(mx, vals[i]); }
    #pragma unroll
    for (int o=32;o>0;o>>=1) mx = fmaxf(mx, __shfl_down(mx, o));
    int lane = tid & 63, wid = tid >> 6;
    if (lane == 0) red[wid] = mx;
    __syncthreads();
    if (tid == 0) red[4] = fmaxf(fmaxf(red[0],red[1]), fmaxf(red[2],red[3]));
    __syncthreads();
    mx = red[4];
    float sum = 0.f;
    #pragma unroll
    for (int i=0;i<16;i++){ vals[i] = expf(vals[i]-mx); sum += vals[i]; }
    #pragma unroll
    for (int o=32;o>0;o>>=1) sum += __shfl_down(sum, o);
    if (lane == 0) red[wid] = sum;
    __syncthreads();
    if (tid == 0) red[5] = red[0]+red[1]+red[2]+red[3];
    __syncthreads();
    float inv = 1.f/red[5];
    #pragma unroll
    for (int i=0;i<16;i++){
        float ab = vals[i]*inv*LD(&bmp[i*256+tid]);
        ST(&bmp[i*256+tid], ab);
    }
}

// ---------- h[lb][c][s] += sum_{l in K-slice} xn[c,l]*AB[s,l]; 32 slices, atomic ----------
__global__ __launch_bounds__(256) void h_mfma(
        const ushort* __restrict__ xn_bf, const bf16* __restrict__ bc,
        float* __restrict__ h)
{
    int blk = blockIdx.x;
    int lb = blk >> 5;
    int kz = blk & 31;
    int kbase = kz*128;
    int tid = threadIdx.x, lane = tid & 63, w = tid >> 6;
    const ushort* ap = xn_bf + (size_t)lb*256*4096;
    const ushort* bp = (const ushort*)bc + (size_t)lb*192*4096;
    f32x4 zero4 = {0.f,0.f,0.f,0.f};
    f32x4 acc[4][4];
    #pragma unroll
    for (int m=0;m<4;m++)
        #pragma unroll
        for (int n=0;n<4;n++) acc[m][n] = zero4;

    #pragma unroll
    for (int ks=0; ks<4; ks++){
        int koff = kbase + ks*32 + (lane>>4)*8;
        bf16x8 afr[4], bfr[4];
        #pragma unroll
        for (int m=0;m<4;m++)
            afr[m] = *(const bf16x8*)&ap[(size_t)(w*64 + m*16 + (lane&15))*4096 + koff];
        #pragma unroll
        for (int n=0;n<4;n++)
            bfr[n] = *(const bf16x8*)&bp[(size_t)(n*16 + (lane&15))*4096 + koff];
        #pragma unroll
        for (int m=0;m<4;m++)
            #pragma unroll
            for (int n=0;n<4;n++)
                acc[m][n] = __builtin_amdgcn_mfma_f32_16x16x32_bf16(afr[m], bfr[n], acc[m][n], 0,0,0);
    }
    float* hp = h + (size_t)lb*16384;
    #pragma unroll
    for (int m=0;m<4;m++)
        #pragma unroll
        for (int n=0;n<4;n++)
            #pragma unroll
            for (int r=0;r<4;r++){
                int c = w*64 + m*16 + (lane>>4)*4 + r;
                int s = n*16 + (lane&15);
                atomicAdd(&hp[c*64 + s], acc[m][n][r]);
            }
}

// ---------- fused: hz (both halves) + silu gate -> hg (reads pre-summed h) ----------
__global__ __launch_bounds__(256) void hz_gate(const float* __restrict__ h,
        const float* __restrict__ w, const float* __restrict__ Dp,
        float* __restrict__ hg)
{
    __shared__ float ht[256][64];
    int blk = blockIdx.x; int lb = blk>>2; int o0 = (blk&3)*64;
    int tid = threadIdx.x;
    const float* hp = h + (size_t)lb*16384;
    for (int i=tid;i<16384;i+=256) ht[i>>6][i&63] = hp[i];
    __syncthreads();
    int lane=tid&63, g=tid>>6;
    float Dv = Dp[0];
    for (int i4=0;i4<4;i4++){
        int ol = o0 + g*16 + i4*4;
        const float* r0 = w + (size_t)ol*256;            // hh rows
        const float *r1=r0+256, *r2=r0+512, *r3=r0+768;
        const float* z0 = w + (size_t)(ol+256)*256;      // z rows
        const float *z1=z0+256, *z2=z0+512, *z3=z0+768;
        float d0=0.f,d1=0.f,d2=0.f,d3=0.f;
        float e0=0.f,e1=0.f,e2=0.f,e3=0.f;
        #pragma unroll 4
        for (int c4=0;c4<64;c4++){
            float x0=ht[c4*4][lane],x1v=ht[c4*4+1][lane],x2v=ht[c4*4+2][lane],x3v=ht[c4*4+3][lane];
            float4 a0=((const float4*)r0)[c4],a1=((const float4*)r1)[c4];
            float4 a2=((const float4*)r2)[c4],a3=((const float4*)r3)[c4];
            d0 += a0.x*x0+a0.y*x1v+a0.z*x2v+a0.w*x3v;
            d1 += a1.x*x0+a1.y*x1v+a1.z*x2v+a1.w*x3v;
            d2 += a2.x*x0+a2.y*x1v+a2.z*x2v+a2.w*x3v;
            d3 += a3.x*x0+a3.y*x1v+a3.z*x2v+a3.w*x3v;
            float4 b0=((const float4*)z0)[c4],b1=((const float4*)z1)[c4];
            float4 b2=((const float4*)z2)[c4],b3=((const float4*)z3)[c4];
            e0 += b0.x*x0+b0.y*x1v+b0.z*x2v+b0.w*x3v;
            e1 += b1.x*x0+b1.y*x1v+b1.z*x2v+b1.w*x3v;
            e2 += b2.x*x0+b2.y*x1v+b2.z*x2v+b2.w*x3v;
            e3 += b3.x*x0+b3.y*x1v+b3.z*x2v+b3.w*x3v;
        }
        float s0 = e0/(1.f+expf(-e0)) + Dv;
        float s1 = e1/(1.f+expf(-e1)) + Dv;
        float s2 = e2/(1.f+expf(-e2)) + Dv;
        float s3 = e3/(1.f+expf(-e3)) + Dv;
        size_t base = ((size_t)lb*256 + ol)*64 + lane;
        hg[base]=d0*s0; hg[base+64]=d1*s1; hg[base+128]=d2*s2; hg[base+192]=d3*s3;
    }
}

// ---------- hout = out_w(256,256) @ hg ; writes bf16 ws copy + f32 d_out copy ----------
__global__ __launch_bounds__(256) void out_gemm(const float* __restrict__ hg, const float* __restrict__ w,
        ushort* __restrict__ hout_bf, float* __restrict__ hout_out, int b0)
{
    __shared__ float ht[256][64];
    int blk = blockIdx.x; int lb = blk>>2; int b = b0 + lb; int o0 = (blk&3)*64;
    int tid = threadIdx.x;
    const float* hp = hg + (size_t)lb*16384;
    for (int i=tid;i<16384;i+=256) ht[i>>6][i&63]=hp[i];
    __syncthreads();
    int lane=tid&63, g=tid>>6;
    for (int i4=0;i4<4;i4++){
        int ol = g*16 + i4*4;
        const float* r0 = w + (size_t)(o0+ol)*256;
        const float *r1=r0+256, *r2=r0+512, *r3=r0+768;
        float d0=0.f,d1=0.f,d2=0.f,d3=0.f;
        #pragma unroll 8
        for (int c4=0;c4<64;c4++){
            float x0=ht[c4*4][lane],x1v=ht[c4*4+1][lane],x2v=ht[c4*4+2][lane],x3v=ht[c4*4+3][lane];
            float4 a0=((const float4*)r0)[c4],a1=((const float4*)r1)[c4];
            float4 a2=((const float4*)r2)[c4],a3=((const float4*)r3)[c4];
            d0 += a0.x*x0+a0.y*x1v+a0.z*x2v+a0.w*x3v;
            d1 += a1.x*x0+a1.y*x1v+a1.z*x2v+a1.w*x3v;
            d2 += a2.x*x0+a2.y*x1v+a2.z*x2v+a2.w*x3v;
            d3 += a3.x*x0+a3.y*x1v+a3.z*x2v+a3.w*x3v;
        }
        size_t lbase = ((size_t)lb*256 + o0 + ol)*64 + lane;
        hout_bf[lbase]=f2b(d0); hout_bf[lbase+64]=f2b(d1);
        hout_bf[lbase+128]=f2b(d2); hout_bf[lbase+192]=f2b(d3);
        size_t gbase = ((size_t)b*256 + o0 + ol)*64 + lane;
        hout_out[gbase]=d0; hout_out[gbase+64]=d1;
        hout_out[gbase+128]=d2; hout_out[gbase+192]=d3;
    }
}

// ---------- y = hout @ Cm (MFMA) ; x2 = (1-a1)*x1 + a1*y in place on x1 ----------
template<typename TX>
__global__ __launch_bounds__(256) void y_mfma(
        const ushort* __restrict__ hout_bf, const bf16* __restrict__ bc,
        TX* __restrict__ x1, const float* __restrict__ alpha, int b0)
{
    __shared__ __align__(16) ushort Cs[64*64];   // [px][s] bf16, swizzled
    int blk = blockIdx.x; int lb = blk>>6; int b = b0 + lb; int l0 = (blk&63)<<6;
    int tid = threadIdx.x, lane = tid&63, w = tid>>6;
    const ushort* cp = (const ushort*)bc + ((size_t)lb*192 + 64)*4096 + l0;
    for (int sc = w*8; sc < 64; sc += 32){
        ushort u[8];
        #pragma unroll
        for (int j=0;j<8;j++) u[j] = cp[(size_t)(sc+j)*4096 + lane];
        uint4 pk;
        pk.x = (uint)u[0] | ((uint)u[1]<<16);
        pk.y = (uint)u[2] | ((uint)u[3]<<16);
        pk.z = (uint)u[4] | ((uint)u[5]<<16);
        pk.w = (uint)u[6] | ((uint)u[7]<<16);
        int g = (sc>>3) ^ (lane&7);
        *(uint4*)&Cs[lane*64 + g*8] = pk;
    }
    __syncthreads();

    f32x4 zero4 = {0.f,0.f,0.f,0.f};
    f32x4 acc[4][4];
    #pragma unroll
    for (int m=0;m<4;m++)
        #pragma unroll
        for (int f=0;f<4;f++) acc[m][f] = zero4;

    const ushort* ap = hout_bf + (size_t)lb*256*64;
    #pragma unroll
    for (int ks=0; ks<2; ks++){
        bf16x8 afr[4];
        #pragma unroll
        for (int m=0;m<4;m++)
            afr[m] = *(const bf16x8*)&ap[(size_t)(w*64 + m*16 + (lane&15))*64
                                          + ks*32 + (lane>>4)*8];
        #pragma unroll
        for (int f=0;f<4;f++){
            int px = f*16 + (lane&15);
            int s8 = ks*32 + (lane>>4)*8;
            int g = (s8>>3) ^ (px&7);
            bf16x8 bfr = *(const bf16x8*)&Cs[px*64 + g*8];
            #pragma unroll
            for (int m=0;m<4;m++)
                acc[m][f] = __builtin_amdgcn_mfma_f32_16x16x32_bf16(afr[m], bfr, acc[m][f], 0,0,0);
        }
    }

    TX* xpo = x1 + (size_t)b*256*4096 + l0;
    #pragma unroll
    for (int m=0;m<4;m++)
        #pragma unroll
        for (int r=0;r<4;r++){
            int c = w*64 + m*16 + (lane>>4)*4 + r;
            float av = sigm(alpha[256+c]);
            #pragma unroll
            for (int f=0;f<4;f++){
                int px = f*16 + (lane&15);
                float xv = LD(&xpo[(size_t)c*4096 + px]);
                ST(&xpo[(size_t)c*4096 + px], (1.f-av)*xv + av*acc[m][f][r]);
            }
        }
}

// ---------- MFMA FFN (R5 structure, frozen at ~313us): Xs+Ts LDS, single buffer ----------
template<typename TX>
__global__ __launch_bounds__(256) void ffn_mfma(
        const TX* __restrict__ x,
        const ushort* __restrict__ w1bf,  // [1024][256]
        const ushort* __restrict__ w2bf,  // [256][1024]
        const float* __restrict__ sc1, const float* __restrict__ sb1,
        const float* __restrict__ sc2, const float* __restrict__ sb2,
        const float* __restrict__ alpha,
        float* __restrict__ out)
{
    __shared__ __align__(16) ushort Xs[64*256];  // 32 KB, [px][c] swizzled
    __shared__ __align__(16) ushort Ts[64*128];  // 16 KB, [px][h_local] swizzled
    int blk = blockIdx.x;
    int b = blk >> 6, l0 = (blk & 63) << 6;
    int tid = threadIdx.x, lane = tid & 63, w = tid >> 6;
    const TX* xp = x + (size_t)b*256*4096 + l0;

    for (int cc = w*8; cc < 256; cc += 32) {
        float v[8];
        #pragma unroll
        for (int j=0;j<8;j++) v[j] = LD(&xp[(size_t)(cc+j)*4096 + lane]);
        uint4 pk;
        pk.x = (uint)f2b(v[0]) | ((uint)f2b(v[1])<<16);
        pk.y = (uint)f2b(v[2]) | ((uint)f2b(v[3])<<16);
        pk.z = (uint)f2b(v[4]) | ((uint)f2b(v[5])<<16);
        pk.w = (uint)f2b(v[6]) | ((uint)f2b(v[7])<<16);
        int g = (cc>>3) ^ (lane&7);
        *(uint4*)&Xs[lane*256 + g*8] = pk;
    }
    __syncthreads();

    f32x4 zero4 = {0.f,0.f,0.f,0.f};
    f32x4 acc2[4][4];
    #pragma unroll
    for (int m=0;m<4;m++)
        #pragma unroll
        for (int f=0;f<4;f++) acc2[m][f] = zero4;

    for (int hc = 0; hc < 1024; hc += 128) {
        int hbase = hc + w*32;
        f32x4 c1[2][4];
        #pragma unroll
        for (int m=0;m<2;m++)
            #pragma unroll
            for (int f=0;f<4;f++) c1[m][f] = zero4;
        for (int ks = 0; ks < 8; ks++) {
            bf16x8 afr[2];
            #pragma unroll
            for (int m=0;m<2;m++)
                afr[m] = *(const bf16x8*)&w1bf[(size_t)(hbase + m*16 + (lane&15))*256
                                               + ks*32 + (lane>>4)*8];
            #pragma unroll
            for (int f=0;f<4;f++){
                int px = f*16 + (lane&15);
                int g = (ks*4 + (lane>>4)) ^ (px&7);
                bf16x8 bfr = *(const bf16x8*)&Xs[px*256 + g*8];
                #pragma unroll
                for (int m=0;m<2;m++)
                    c1[m][f] = __builtin_amdgcn_mfma_f32_16x16x32_bf16(afr[m], bfr, c1[m][f], 0,0,0);
            }
        }
        __syncthreads();   // prev GEMM2 readers of Ts done
        #pragma unroll
        for (int m=0;m<2;m++){
            #pragma unroll
            for (int r=0;r<4;r++){
                int h = hbase + m*16 + (lane>>4)*4 + r;
                float s1 = sc1[h], bb1 = sb1[h];
                int hl = h - hc;
                #pragma unroll
                for (int f=0;f<4;f++){
                    int px = f*16 + (lane&15);
                    float t = fmaxf(c1[m][f][r]*s1 + bb1, 0.f);
                    int g = (hl>>3) ^ (px&7);
                    Ts[px*128 + g*8 + (hl&7)] = f2b(t);
                }
            }
        }
        __syncthreads();
        int c0 = w*64;
        for (int ks = 0; ks < 4; ks++) {
            bf16x8 afr[4];
            #pragma unroll
            for (int m=0;m<4;m++)
                afr[m] = *(const bf16x8*)&w2bf[(size_t)(c0 + m*16 + (lane&15))*1024
                                               + hc + ks*32 + (lane>>4)*8];
            #pragma unroll
            for (int f=0;f<4;f++){
                int px = f*16 + (lane&15);
                int hl = ks*32 + (lane>>4)*8;
                int g = (hl>>3) ^ (px&7);
                bf16x8 bfr = *(const bf16x8*)&Ts[px*128 + g*8];
                #pragma unroll
                for (int m=0;m<4;m++)
                    acc2[m][f] = __builtin_amdgcn_mfma_f32_16x16x32_bf16(afr[m], bfr, acc2[m][f], 0,0,0);
            }
        }
    }

    float* op = out + (size_t)b*256*4096 + l0;
    int c0 = w*64;
    #pragma unroll
    for (int m=0;m<4;m++){
        #pragma unroll
        for (int r=0;r<4;r++){
            int c = c0 + m*16 + (lane>>4)*4 + r;
            float a = sigm(alpha[768+c]);
            float s2 = sc2[c], bb2 = sb2[c];
            #pragma unroll
            for (int f=0;f<4;f++){
                int px = f*16 + (lane&15);
                float t2 = acc2[m][f][r]*s2 + bb2;
                float xv = LD(&xp[(size_t)c*4096 + px]);
                op[(size_t)c*4096 + px] = (1.f-a)*xv + a*t2;
            }
        }
    }
}

// ---------- pipeline (templated on residual-stream storage type) ----------
template<typename TX>
static void run_all(const float* x, TX* x1, float* d_out_x, float* hout_out,
                    const float* dw1w, const float* dw1g, const float* dw1b,
                    const float* dw1m, const float* dw1v,
                    const float* lnw, const float* lnb,
                    const ushort* wbc, const float* dwmw, const float* Ap,
                    const float* hzw, const float* outw, const float* Dp,
                    const float* dw2w, const float* dw2g, const float* dw2b,
                    const float* dw2m, const float* dw2v,
                    const ushort* w1bf, const ushort* w2bf,
                    const float* sc1, const float* sb1,
                    const float* sc2, const float* sb2,
                    const float* alpha,
                    float* meanp, float* invp, char* cbase, int NB,
                    hipStream_t stream)
{
    bf16*   bc      = (bf16*)cbase;
    ushort* xn_bf   = (ushort*)(cbase + (size_t)NB*1572864);
    float*  h       = (float*)(cbase + (size_t)NB*(1572864 + 2097152));
    float*  hg      = (float*)((char*)h + (size_t)NB*65536);
    ushort* hout_bf = (ushort*)((char*)hg + (size_t)NB*65536);

    dwconv_bn_blend<float,TX><<<8192,256,0,stream>>>(x, x1, dw1w,dw1g,dw1b,dw1m,dw1v, alpha, 0);
    if constexpr (std::is_same<TX,bf16>::value)
        ln_stats_bf<<<256,256,0,stream>>>(x1, meanp, invp);
    else
        ln_stats_f<<<512,256,0,stream>>>((const float*)x1, meanp, invp);

    for (int b0 = 0; b0 < 32; b0 += NB) {
        bcdt_mfma<TX><<<NB*64,256,0,stream>>>(x1, meanp, invp, lnw, lnb, wbc, bc, xn_bf, b0);
        dwconv_plain<<<NB*192,256,0,stream>>>(bc, dwmw);
        softmax_ab<<<NB*64,256,0,stream>>>(bc, Ap);
        hipMemsetAsync(h, 0, (size_t)NB*65536, stream);
        h_mfma<<<NB*32,256,0,stream>>>(xn_bf, bc, h);
        hz_gate<<<NB*4,256,0,stream>>>(h, hzw, Dp, hg);
        out_gemm<<<NB*4,256,0,stream>>>(hg, outw, hout_bf, hout_out, b0);
        y_mfma<TX><<<NB*64,256,0,stream>>>(hout_bf, bc, x1, alpha, b0);
    }

    dwconv_bn_blend<TX,TX><<<8192,256,0,stream>>>(x1, x1, dw2w,dw2g,dw2b,dw2m,dw2v, alpha, 2);
    ffn_mfma<TX><<<2048,256,0,stream>>>(x1, w1bf, w2bf, sc1, sb1, sc2, sb2, alpha, d_out_x);
}

extern "C" void kernel_launch(void* const* d_in, const int* in_sizes, int n_in,
                              void* d_out, int out_size, void* d_ws, size_t ws_size,
                              hipStream_t stream)
{
    (void)in_sizes; (void)n_in; (void)out_size;
    const float* x     = (const float*)d_in[0];
    const float* dw1w  = (const float*)d_in[1];
    const float* dw1g  = (const float*)d_in[2];
    const float* dw1b  = (const float*)d_in[3];
    const float* dw1m  = (const float*)d_in[4];
    const float* dw1v  = (const float*)d_in[5];
    const float* lnw   = (const float*)d_in[6];
    const float* lnb   = (const float*)d_in[7];
    const float* bcdtw = (const float*)d_in[8];
    const float* dwmw  = (const float*)d_in[9];
    const float* Ap    = (const float*)d_in[10];
    const float* hzw   = (const float*)d_in[11];
    const float* outw  = (const float*)d_in[12];
    const float* Dp    = (const float*)d_in[13];
    const float* dw2w  = (const float*)d_in[14];
    const float* dw2g  = (const float*)d_in[15];
    const float* dw2b  = (const float*)d_in[16];
    const float* dw2m  = (const float*)d_in[17];
    const float* dw2v  = (const float*)d_in[18];
    const float* f1w   = (const float*)d_in[19];
    const float* f1g   = (const float*)d_in[20];
    const float* f1b   = (const float*)d_in[21];
    const float* f1m   = (const float*)d_in[22];
    const float* f1v   = (const float*)d_in[23];
    const float* f2w   = (const float*)d_in[24];
    const float* f2g   = (const float*)d_in[25];
    const float* f2b_  = (const float*)d_in[26];
    const float* f2m   = (const float*)d_in[27];
    const float* f2v   = (const float*)d_in[28];
    const float* alpha = (const float*)d_in[29];

    const size_t nx = (size_t)32*256*4096;
    float* d_out_x  = (float*)d_out;
    float* hout_out = d_out_x + nx;

    char* ws = (char*)d_ws;
    float* meanp = (float*)ws;                       // 512 KB
    float* invp  = meanp + 131072;                   // 512 KB
    size_t off = 1048576;
    ushort* w1bf = (ushort*)(ws + off); off += 524288;
    ushort* w2bf = (ushort*)(ws + off); off += 524288;
    ushort* wbc  = (ushort*)(ws + off); off += 98304;
    float* sc1 = (float*)(ws + off); off += 4096;
    float* sb1 = (float*)(ws + off); off += 4096;
    float* sc2 = (float*)(ws + off); off += 1024;
    float* sb2 = (float*)(ws + off); off += 1024;
    off = (off + 255) & ~(size_t)255;

    // per-b: bc 1.5M + xn_bf 2M + h 64K + hg 64K + hout_bf 32K
    const size_t perb = 1572864 + 2097152 + 65536 + 65536 + 32768; // 3,833,856
    size_t avail = ws_size > off ? ws_size - off : 0;

    prep_k<<<1024,256,0,stream>>>(f1w, f2w, bcdtw, f1g,f1b,f1m,f1v, f2g,f2b_,f2m,f2v,
                                  w1bf, w2bf, wbc, sc1, sb1, sc2, sb2);

    // Prefer bf16 residual stream (halves x1 traffic) when ws fits x1_bf + NB>=8 chunks.
    if (avail >= nx*2 + 8*perb) {
        bf16* x1b = (bf16*)(ws + off); off += nx*2;
        char* cbase = ws + off;
        size_t a2 = ws_size - off;
        int NB = 8;
        for (int nb = 32; nb >= 8; nb >>= 1) if (a2 >= (size_t)nb*perb) { NB = nb; break; }
        run_all<bf16>(x, x1b, d_out_x, hout_out,
                      dw1w,dw1g,dw1b,dw1m,dw1v, lnw,lnb, wbc, dwmw, Ap, hzw, outw, Dp,
                      dw2w,dw2g,dw2b,dw2m,dw2v, w1bf,w2bf, sc1,sb1,sc2,sb2, alpha,
                      meanp, invp, cbase, NB, stream);
    } else {
        char* cbase = ws + off;
        int NB = 1;
        for (int nb = 32; nb >= 1; nb >>= 1) if (avail >= (size_t)nb*perb) { NB = nb; break; }
        run_all<float>(x, d_out_x, d_out_x, hout_out,
                       dw1w,dw1g,dw1b,dw1m,dw1v, lnw,lnb, wbc, dwmw, Ap, hzw, outw, Dp,
                       dw2w,dw2g,dw2b,dw2m,dw2v, w1bf,w2bf, sc1,sb1,sc2,sb2, alpha,
                       meanp, invp, cbase, NB, stream);
    }
}

// Round 17
// 663.282 us; speedup vs baseline: 1.0596x; 1.0596x over previous
//
#include <hip/hip_runtime.h>
#include <hip/hip_bf16.h>
#include <type_traits>

typedef __hip_bfloat16 bf16;
typedef __attribute__((ext_vector_type(8))) short bf16x8;
typedef __attribute__((ext_vector_type(4))) float f32x4;

// ---------- helpers ----------
__device__ __forceinline__ float LD(const float* p){ return *p; }
__device__ __forceinline__ float LD(const bf16* p){ return __bfloat162float(*p); }
__device__ __forceinline__ void ST(float* p, float v){ *p = v; }
__device__ __forceinline__ void ST(bf16* p, float v){ *p = __float2bfloat16(v); }
__device__ __forceinline__ float sigm(float v){ return 1.f/(1.f + expf(-v)); }
__device__ __forceinline__ ushort f2b(float f){            // RNE f32->bf16 bits
    unsigned u = __float_as_uint(f);
    return (ushort)((u + 0x7fffu + ((u>>16)&1u)) >> 16);
}

#define NEPS 1e-5f

// ---------- dwconv tile staging: 66x66 padded tile from a 64x64 plane ----------
__device__ __forceinline__ void stage_tile(const float* __restrict__ xp, float* tile, int tid){
    for (int i = tid; i < 66*66; i += 256) {
        int r = i/66, c = i%66;
        int gr = r-1, gc = c-1;
        float val = 0.f;
        if (gr >= 0 && gr < 64 && gc >= 0 && gc < 64) val = xp[gr*64+gc];
        tile[i] = val;
    }
}
__device__ __forceinline__ void stage_tile(const bf16* __restrict__ xp, float* tile, int tid){
    for (int i = tid; i < 2048; i += 256) {
        int r = i >> 5, c = (i & 31) << 1;
        uint u = *(const uint*)((const ushort*)xp + r*64 + c);
        tile[(r+1)*66 + c+1] = __uint_as_float(u << 16);
        tile[(r+1)*66 + c+2] = __uint_as_float(u & 0xffff0000u);
    }
    for (int i = tid; i < 260; i += 256) {
        int tr, tc;
        if (i < 66)       { tr = 0;      tc = i; }
        else if (i < 132) { tr = 65;     tc = i-66; }
        else if (i < 196) { tr = i-131;  tc = 0; }
        else              { tr = i-195;  tc = 65; }
        tile[tr*66 + tc] = 0.f;
    }
}
__device__ __forceinline__ void st_pair(float* op, int idx, float a, float b){
    op[idx] = a; op[idx+1] = b;
}
__device__ __forceinline__ void st_pair(bf16* op, int idx, float a, float b){
    uint u = (uint)f2b(a) | ((uint)f2b(b)<<16);
    *(uint*)((ushort*)op + idx) = u;
}

// ---------- depthwise 3x3 + BN + alpha blend (one block per (b,ch) plane) ----------
template<typename TIN, typename TOUT>
__global__ __launch_bounds__(256) void dwconv_bn_blend(
        const TIN* __restrict__ xin, TOUT* __restrict__ xout,
        const float* __restrict__ w, const float* __restrict__ gg, const float* __restrict__ bb,
        const float* __restrict__ mm, const float* __restrict__ vv,
        const float* __restrict__ alpha, int arow)
{
    __shared__ float tile[66*66];
    int blk = blockIdx.x;
    int ch = blk & 255;
    const TIN* xp = xin + (size_t)blk*4096;
    TOUT* op = xout + (size_t)blk*4096;
    int tid = threadIdx.x;
    stage_tile(xp, tile, tid);
    __syncthreads();
    float wv[9];
    #pragma unroll
    for (int k=0;k<9;k++) wv[k] = w[ch*9+k];
    float sc = gg[ch] * rsqrtf(vv[ch] + NEPS);
    float mv = mm[ch], bv = bb[ch];
    float av = sigm(alpha[arow*256+ch]);
    for (int p2 = tid; p2 < 2048; p2 += 256) {
        int r = p2 >> 5, c = (p2 & 31) << 1;
        float a0 = 0.f, a1 = 0.f;
        #pragma unroll
        for (int dr=0;dr<3;dr++)
            #pragma unroll
            for (int dc=0;dc<3;dc++){
                float wk = wv[dr*3+dc];
                a0 += wk*tile[(r+dr)*66 + c+dc];
                a1 += wk*tile[(r+dr)*66 + c+1+dc];
            }
        float bn0 = (a0 - mv)*sc + bv;
        float bn1 = (a1 - mv)*sc + bv;
        float xv0 = tile[(r+1)*66 + c+1];
        float xv1 = tile[(r+1)*66 + c+2];
        st_pair(op, r*64+c, (1.f-av)*xv0 + av*bn0, (1.f-av)*xv1 + av*bn1);
    }
}

// ---------- LayerNorm stats (f32 path) ----------
__global__ __launch_bounds__(256) void ln_stats_f(const float* __restrict__ x1,
        float* __restrict__ meanp, float* __restrict__ invp)
{
    int blk = blockIdx.x;
    int b = blk >> 4;
    int l = ((blk & 15) << 8) + threadIdx.x;
    const float* xp = x1 + (size_t)b*256*4096 + l;
    float mean = 0.f, m2 = 0.f;
    for (int c=0;c<256;c++){ float v = xp[(size_t)c*4096]; mean += v; m2 += v*v; }
    mean *= (1.f/256.f); m2 *= (1.f/256.f);
    meanp[b*4096 + l] = mean;
    invp[b*4096 + l] = rsqrtf(m2 - mean*mean + NEPS);
}

// ---------- LayerNorm stats (bf16 path, 2 columns/thread via uint loads) ----------
__global__ __launch_bounds__(256) void ln_stats_bf(const bf16* __restrict__ x1,
        float* __restrict__ meanp, float* __restrict__ invp)
{
    int blk = blockIdx.x;
    int b = blk >> 3;
    int l = ((blk & 7) << 9) + (threadIdx.x << 1);
    const ushort* xp = (const ushort*)x1 + (size_t)b*256*4096 + l;
    float mean0 = 0.f, m20 = 0.f, mean1 = 0.f, m21 = 0.f;
    for (int c=0;c<256;c++){
        uint u = *(const uint*)&xp[(size_t)c*4096];
        float v0 = __uint_as_float(u << 16);
        float v1 = __uint_as_float(u & 0xffff0000u);
        mean0 += v0; m20 += v0*v0;
        mean1 += v1; m21 += v1*v1;
    }
    mean0 *= (1.f/256.f); m20 *= (1.f/256.f);
    mean1 *= (1.f/256.f); m21 *= (1.f/256.f);
    meanp[b*4096 + l]   = mean0;
    meanp[b*4096 + l+1] = mean1;
    invp[b*4096 + l]   = rsqrtf(m20 - mean0*mean0 + NEPS);
    invp[b*4096 + l+1] = rsqrtf(m21 - mean1*mean1 + NEPS);
}

// ---------- prep: weights->bf16, fold BN ----------
__global__ __launch_bounds__(256) void prep_k(
        const float* __restrict__ f1w, const float* __restrict__ f2w,
        const float* __restrict__ bcdtw,
        const float* __restrict__ g1, const float* __restrict__ b1,
        const float* __restrict__ m1, const float* __restrict__ v1,
        const float* __restrict__ g2, const float* __restrict__ b2,
        const float* __restrict__ m2, const float* __restrict__ v2,
        ushort* __restrict__ w1bf, ushort* __restrict__ w2bf,
        ushort* __restrict__ wbc,
        float* __restrict__ sc1, float* __restrict__ sb1,
        float* __restrict__ sc2, float* __restrict__ sb2)
{
    int i = blockIdx.x*256 + threadIdx.x;
    if (i < 262144) {
        w1bf[i] = f2b(f1w[i]);
        w2bf[i] = f2b(f2w[i]);
    }
    if (i < 49152) wbc[i] = f2b(bcdtw[i]);
    if (i < 1024) { float s = g1[i]*rsqrtf(v1[i]+NEPS); sc1[i]=s; sb1[i]=b1[i]-m1[i]*s; }
    if (i < 256)  { float s = g2[i]*rsqrtf(v2[i]+NEPS); sc2[i]=s; sb2[i]=b2[i]-m2[i]*s; }
}

// ---------- bc_dt = bcdt_w(192,256) @ LN(x1), MFMA; side-writes xn_bf ----------
template<typename TX>
__global__ __launch_bounds__(256) void bcdt_mfma(
        const TX* __restrict__ x1,
        const float* __restrict__ meanp, const float* __restrict__ invp,
        const float* __restrict__ lnw, const float* __restrict__ lnb,
        const ushort* __restrict__ wbc,      // [192][256] bf16
        bf16* __restrict__ bc, ushort* __restrict__ xn_bf, int b0)
{
    __shared__ __align__(16) ushort Xs[64*256];  // [px][c] bf16, 16B-block XOR swizzle
    int blk = blockIdx.x;
    int lb = blk >> 6;
    int b  = b0 + lb;
    int l0 = (blk & 63) << 6;
    int tid = threadIdx.x, lane = tid & 63, w = tid >> 6;
    const TX* xp = x1 + (size_t)b*256*4096 + l0;
    float mval = meanp[b*4096 + l0 + lane];
    float ival = invp [b*4096 + l0 + lane];
    ushort* xnp = xn_bf + (size_t)lb*256*4096 + l0;

    for (int cc = w*8; cc < 256; cc += 32) {
        ushort u[8];
        #pragma unroll
        for (int j=0;j<8;j++){
            float v = LD(&xp[(size_t)(cc+j)*4096 + lane]);
            float xn = (v - mval)*ival*lnw[cc+j] + lnb[cc+j];
            u[j] = f2b(xn);
            xnp[(size_t)(cc+j)*4096 + lane] = u[j];
        }
        uint4 pk;
        pk.x = (uint)u[0] | ((uint)u[1]<<16);
        pk.y = (uint)u[2] | ((uint)u[3]<<16);
        pk.z = (uint)u[4] | ((uint)u[5]<<16);
        pk.w = (uint)u[6] | ((uint)u[7]<<16);
        int g = (cc>>3) ^ (lane&7);
        *(uint4*)&Xs[lane*256 + g*8] = pk;
    }
    __syncthreads();

    f32x4 zero4 = {0.f,0.f,0.f,0.f};
    f32x4 acc[3][4];
    #pragma unroll
    for (int m=0;m<3;m++)
        #pragma unroll
        for (int f=0;f<4;f++) acc[m][f] = zero4;

    int hbase = w*48;
    #pragma unroll
    for (int ks=0; ks<8; ks++){
        bf16x8 afr[3];
        #pragma unroll
        for (int m=0;m<3;m++)
            afr[m] = *(const bf16x8*)&wbc[(size_t)(hbase + m*16 + (lane&15))*256
                                          + ks*32 + (lane>>4)*8];
        #pragma unroll
        for (int f=0;f<4;f++){
            int px = f*16 + (lane&15);
            int g = (ks*4 + (lane>>4)) ^ (px&7);
            bf16x8 bfr = *(const bf16x8*)&Xs[px*256 + g*8];
            #pragma unroll
            for (int m=0;m<3;m++)
                acc[m][f] = __builtin_amdgcn_mfma_f32_16x16x32_bf16(afr[m], bfr, acc[m][f], 0,0,0);
        }
    }
    bf16* op = bc + (size_t)lb*192*4096 + l0;
    #pragma unroll
    for (int m=0;m<3;m++)
        #pragma unroll
        for (int r=0;r<4;r++){
            int o = hbase + m*16 + (lane>>4)*4 + r;
            #pragma unroll
            for (int f=0;f<4;f++){
                int px = f*16 + (lane&15);
                op[(size_t)o*4096 + px] = __float2bfloat16(acc[m][f][r]);
            }
        }
}

// ---------- plain depthwise 3x3, in-place (192 channels per batch), bf16 ----------
__global__ __launch_bounds__(256) void dwconv_plain(bf16* __restrict__ data, const float* __restrict__ w)
{
    __shared__ float tile[66*66];
    int blk = blockIdx.x;
    int ch = blk % 192;
    bf16* xp = data + (size_t)blk*4096;
    int tid = threadIdx.x;
    stage_tile(xp, tile, tid);
    __syncthreads();
    float wv[9];
    #pragma unroll
    for (int k=0;k<9;k++) wv[k] = w[ch*9+k];
    for (int p2 = tid; p2 < 2048; p2 += 256) {
        int r = p2 >> 5, c = (p2 & 31) << 1;
        float a0 = 0.f, a1 = 0.f;
        #pragma unroll
        for (int dr=0;dr<3;dr++)
            #pragma unroll
            for (int dc=0;dc<3;dc++){
                float wk = wv[dr*3+dc];
                a0 += wk*tile[(r+dr)*66 + c+dc];
                a1 += wk*tile[(r+dr)*66 + c+1+dc];
            }
        st_pair(xp, r*64+c, a0, a1);
    }
}

// ---------- softmax over L (per (lb,s)) and AB = Am*Bm in place over Bm rows ----------
__global__ __launch_bounds__(256) void softmax_ab(bf16* __restrict__ bc, const float* __restrict__ A)
{
    __shared__ float red[8];
    int blk = blockIdx.x;
    int lb = blk >> 6;
    int s = blk & 63;
    bf16* dtp = bc + ((size_t)lb*192 + 128 + s)*4096;
    bf16* bmp = bc + ((size_t)lb*192 + s)*4096;
    int tid = threadIdx.x;
    float Av = A[s];
    float vals[16];
    float mx = -1e30f;
    #pragma unroll
    for (int i=0;i<16;i++){ vals[i] = LD(&dtp[i*256+tid]) + Av; mx = fmaxf(mx, vals[i]); }
    #pragma unroll
    for (int o=32;o>0;o>>=1) mx = fmaxf(mx, __shfl_down(mx, o));
    int lane = tid & 63, wid = tid >> 6;
    if (lane == 0) red[wid] = mx;
    __syncthreads();
    if (tid == 0) red[4] = fmaxf(fmaxf(red[0],red[1]), fmaxf(red[2],red[3]));
    __syncthreads();
    mx = red[4];
    float sum = 0.f;
    #pragma unroll
    for (int i=0;i<16;i++){ vals[i] = expf(vals[i]-mx); sum += vals[i]; }
    #pragma unroll
    for (int o=32;o>0;o>>=1) sum += __shfl_down(sum, o);
    if (lane == 0) red[wid] = sum;
    __syncthreads();
    if (tid == 0) red[5] = red[0]+red[1]+red[2]+red[3];
    __syncthreads();
    float inv = 1.f/red[5];
    #pragma unroll
    for (int i=0;i<16;i++){
        float ab = vals[i]*inv*LD(&bmp[i*256+tid]);
        ST(&bmp[i*256+tid], ab);
    }
}

// ---------- h_part[lb][kz][c][s] = sum_{l in slice} xn[c,l]*AB[s,l], MFMA ----------
__global__ __launch_bounds__(256) void h_mfma(
        const ushort* __restrict__ xn_bf, const bf16* __restrict__ bc,
        float* __restrict__ h_part)
{
    int blk = blockIdx.x;
    int lb = blk >> 3;
    int kz = blk & 7;
    int kbase = kz*512;
    int tid = threadIdx.x, lane = tid & 63, w = tid >> 6;
    const ushort* ap = xn_bf + (size_t)lb*256*4096;
    const ushort* bp = (const ushort*)bc + (size_t)lb*192*4096;
    f32x4 zero4 = {0.f,0.f,0.f,0.f};
    f32x4 acc[4][4];
    #pragma unroll
    for (int m=0;m<4;m++)
        #pragma unroll
        for (int n=0;n<4;n++) acc[m][n] = zero4;

    for (int ks=0; ks<16; ks++){
        int koff = kbase + ks*32 + (lane>>4)*8;
        bf16x8 afr[4], bfr[4];
        #pragma unroll
        for (int m=0;m<4;m++)
            afr[m] = *(const bf16x8*)&ap[(size_t)(w*64 + m*16 + (lane&15))*4096 + koff];
        #pragma unroll
        for (int n=0;n<4;n++)
            bfr[n] = *(const bf16x8*)&bp[(size_t)(n*16 + (lane&15))*4096 + koff];
        #pragma unroll
        for (int m=0;m<4;m++)
            #pragma unroll
            for (int n=0;n<4;n++)
                acc[m][n] = __builtin_amdgcn_mfma_f32_16x16x32_bf16(afr[m], bfr[n], acc[m][n], 0,0,0);
    }
    float* hp = h_part + ((size_t)lb*8 + kz)*16384;
    #pragma unroll
    for (int m=0;m<4;m++)
        #pragma unroll
        for (int n=0;n<4;n++)
            #pragma unroll
            for (int r=0;r<4;r++){
                int c = w*64 + m*16 + (lane>>4)*4 + r;
                int s = n*16 + (lane&15);
                hp[c*64 + s] = acc[m][n][r];
            }
}

// ---------- fused: hz (both halves) + silu gate -> hg  (sums 8 h_part slices) ----------
__global__ __launch_bounds__(256) void hz_gate(const float* __restrict__ h_part,
        const float* __restrict__ w, const float* __restrict__ Dp,
        float* __restrict__ hg)
{
    __shared__ float ht[256][64];
    int blk = blockIdx.x; int lb = blk>>2; int o0 = (blk&3)*64;
    int tid = threadIdx.x;
    const float* hp = h_part + (size_t)lb*8*16384;
    for (int i=tid;i<16384;i+=256){
        float s = 0.f;
        #pragma unroll
        for (int k=0;k<8;k++) s += hp[k*16384 + i];
        ht[i>>6][i&63] = s;
    }
    __syncthreads();
    int lane=tid&63, g=tid>>6;
    float Dv = Dp[0];
    for (int i4=0;i4<4;i4++){
        int ol = o0 + g*16 + i4*4;
        const float* r0 = w + (size_t)ol*256;            // hh rows
        const float *r1=r0+256, *r2=r0+512, *r3=r0+768;
        const float* z0 = w + (size_t)(ol+256)*256;      // z rows
        const float *z1=z0+256, *z2=z0+512, *z3=z0+768;
        float d0=0.f,d1=0.f,d2=0.f,d3=0.f;
        float e0=0.f,e1=0.f,e2=0.f,e3=0.f;
        #pragma unroll 4
        for (int c4=0;c4<64;c4++){
            float x0=ht[c4*4][lane],x1v=ht[c4*4+1][lane],x2v=ht[c4*4+2][lane],x3v=ht[c4*4+3][lane];
            float4 a0=((const float4*)r0)[c4],a1=((const float4*)r1)[c4];
            float4 a2=((const float4*)r2)[c4],a3=((const float4*)r3)[c4];
            d0 += a0.x*x0+a0.y*x1v+a0.z*x2v+a0.w*x3v;
            d1 += a1.x*x0+a1.y*x1v+a1.z*x2v+a1.w*x3v;
            d2 += a2.x*x0+a2.y*x1v+a2.z*x2v+a2.w*x3v;
            d3 += a3.x*x0+a3.y*x1v+a3.z*x2v+a3.w*x3v;
            float4 b0=((const float4*)z0)[c4],b1=((const float4*)z1)[c4];
            float4 b2=((const float4*)z2)[c4],b3=((const float4*)z3)[c4];
            e0 += b0.x*x0+b0.y*x1v+b0.z*x2v+b0.w*x3v;
            e1 += b1.x*x0+b1.y*x1v+b1.z*x2v+b1.w*x3v;
            e2 += b2.x*x0+b2.y*x1v+b2.z*x2v+b2.w*x3v;
            e3 += b3.x*x0+b3.y*x1v+b3.z*x2v+b3.w*x3v;
        }
        float s0 = e0/(1.f+expf(-e0)) + Dv;
        float s1 = e1/(1.f+expf(-e1)) + Dv;
        float s2 = e2/(1.f+expf(-e2)) + Dv;
        float s3 = e3/(1.f+expf(-e3)) + Dv;
        size_t base = ((size_t)lb*256 + ol)*64 + lane;
        hg[base]=d0*s0; hg[base+64]=d1*s1; hg[base+128]=d2*s2; hg[base+192]=d3*s3;
    }
}

// ---------- hout = out_w(256,256) @ hg ; writes bf16 ws copy + f32 d_out copy ----------
__global__ __launch_bounds__(256) void out_gemm(const float* __restrict__ hg, const float* __restrict__ w,
        ushort* __restrict__ hout_bf, float* __restrict__ hout_out, int b0)
{
    __shared__ float ht[256][64];
    int blk = blockIdx.x; int lb = blk>>2; int b = b0 + lb; int o0 = (blk&3)*64;
    int tid = threadIdx.x;
    const float* hp = hg + (size_t)lb*16384;
    for (int i=tid;i<16384;i+=256) ht[i>>6][i&63]=hp[i];
    __syncthreads();
    int lane=tid&63, g=tid>>6;
    for (int i4=0;i4<4;i4++){
        int ol = g*16 + i4*4;
        const float* r0 = w + (size_t)(o0+ol)*256;
        const float *r1=r0+256, *r2=r0+512, *r3=r0+768;
        float d0=0.f,d1=0.f,d2=0.f,d3=0.f;
        #pragma unroll 8
        for (int c4=0;c4<64;c4++){
            float x0=ht[c4*4][lane],x1v=ht[c4*4+1][lane],x2v=ht[c4*4+2][lane],x3v=ht[c4*4+3][lane];
            float4 a0=((const float4*)r0)[c4],a1=((const float4*)r1)[c4];
            float4 a2=((const float4*)r2)[c4],a3=((const float4*)r3)[c4];
            d0 += a0.x*x0+a0.y*x1v+a0.z*x2v+a0.w*x3v;
            d1 += a1.x*x0+a1.y*x1v+a1.z*x2v+a1.w*x3v;
            d2 += a2.x*x0+a2.y*x1v+a2.z*x2v+a2.w*x3v;
            d3 += a3.x*x0+a3.y*x1v+a3.z*x2v+a3.w*x3v;
        }
        size_t lbase = ((size_t)lb*256 + o0 + ol)*64 + lane;
        hout_bf[lbase]=f2b(d0); hout_bf[lbase+64]=f2b(d1);
        hout_bf[lbase+128]=f2b(d2); hout_bf[lbase+192]=f2b(d3);
        size_t gbase = ((size_t)b*256 + o0 + ol)*64 + lane;
        hout_out[gbase]=d0; hout_out[gbase+64]=d1;
        hout_out[gbase+128]=d2; hout_out[gbase+192]=d3;
    }
}

// ---------- y = hout @ Cm (MFMA) ; x2 = (1-a1)*x1 + a1*y in place on x1 ----------
template<typename TX>
__global__ __launch_bounds__(256) void y_mfma(
        const ushort* __restrict__ hout_bf, const bf16* __restrict__ bc,
        TX* __restrict__ x1, const float* __restrict__ alpha, int b0)
{
    __shared__ __align__(16) ushort Cs[64*64];   // [px][s] bf16, swizzled
    int blk = blockIdx.x; int lb = blk>>6; int b = b0 + lb; int l0 = (blk&63)<<6;
    int tid = threadIdx.x, lane = tid&63, w = tid>>6;
    const ushort* cp = (const ushort*)bc + ((size_t)lb*192 + 64)*4096 + l0;
    for (int sc = w*8; sc < 64; sc += 32){
        ushort u[8];
        #pragma unroll
        for (int j=0;j<8;j++) u[j] = cp[(size_t)(sc+j)*4096 + lane];
        uint4 pk;
        pk.x = (uint)u[0] | ((uint)u[1]<<16);
        pk.y = (uint)u[2] | ((uint)u[3]<<16);
        pk.z = (uint)u[4] | ((uint)u[5]<<16);
        pk.w = (uint)u[6] | ((uint)u[7]<<16);
        int g = (sc>>3) ^ (lane&7);
        *(uint4*)&Cs[lane*64 + g*8] = pk;
    }
    __syncthreads();

    f32x4 zero4 = {0.f,0.f,0.f,0.f};
    f32x4 acc[4][4];
    #pragma unroll
    for (int m=0;m<4;m++)
        #pragma unroll
        for (int f=0;f<4;f++) acc[m][f] = zero4;

    const ushort* ap = hout_bf + (size_t)lb*256*64;
    #pragma unroll
    for (int ks=0; ks<2; ks++){
        bf16x8 afr[4];
        #pragma unroll
        for (int m=0;m<4;m++)
            afr[m] = *(const bf16x8*)&ap[(size_t)(w*64 + m*16 + (lane&15))*64
                                          + ks*32 + (lane>>4)*8];
        #pragma unroll
        for (int f=0;f<4;f++){
            int px = f*16 + (lane&15);
            int s8 = ks*32 + (lane>>4)*8;
            int g = (s8>>3) ^ (px&7);
            bf16x8 bfr = *(const bf16x8*)&Cs[px*64 + g*8];
            #pragma unroll
            for (int m=0;m<4;m++)
                acc[m][f] = __builtin_amdgcn_mfma_f32_16x16x32_bf16(afr[m], bfr, acc[m][f], 0,0,0);
        }
    }

    TX* xpo = x1 + (size_t)b*256*4096 + l0;
    #pragma unroll
    for (int m=0;m<4;m++)
        #pragma unroll
        for (int r=0;r<4;r++){
            int c = w*64 + m*16 + (lane>>4)*4 + r;
            float av = sigm(alpha[256+c]);
            #pragma unroll
            for (int f=0;f<4;f++){
                int px = f*16 + (lane&15);
                float xv = LD(&xpo[(size_t)c*4096 + px]);
                ST(&xpo[(size_t)c*4096 + px], (1.f-av)*xv + av*acc[m][f][r]);
            }
        }
}

// ---------- MFMA FFN (R5 structure, frozen at ~313us): Xs+Ts LDS, single buffer ----------
template<typename TX>
__global__ __launch_bounds__(256) void ffn_mfma(
        const TX* __restrict__ x,
        const ushort* __restrict__ w1bf,  // [1024][256]
        const ushort* __restrict__ w2bf,  // [256][1024]
        const float* __restrict__ sc1, const float* __restrict__ sb1,
        const float* __restrict__ sc2, const float* __restrict__ sb2,
        const float* __restrict__ alpha,
        float* __restrict__ out)
{
    __shared__ __align__(16) ushort Xs[64*256];  // 32 KB, [px][c] swizzled
    __shared__ __align__(16) ushort Ts[64*128];  // 16 KB, [px][h_local] swizzled
    int blk = blockIdx.x;
    int b = blk >> 6, l0 = (blk & 63) << 6;
    int tid = threadIdx.x, lane = tid & 63, w = tid >> 6;
    const TX* xp = x + (size_t)b*256*4096 + l0;

    for (int cc = w*8; cc < 256; cc += 32) {
        float v[8];
        #pragma unroll
        for (int j=0;j<8;j++) v[j] = LD(&xp[(size_t)(cc+j)*4096 + lane]);
        uint4 pk;
        pk.x = (uint)f2b(v[0]) | ((uint)f2b(v[1])<<16);
        pk.y = (uint)f2b(v[2]) | ((uint)f2b(v[3])<<16);
        pk.z = (uint)f2b(v[4]) | ((uint)f2b(v[5])<<16);
        pk.w = (uint)f2b(v[6]) | ((uint)f2b(v[7])<<16);
        int g = (cc>>3) ^ (lane&7);
        *(uint4*)&Xs[lane*256 + g*8] = pk;
    }
    __syncthreads();

    f32x4 zero4 = {0.f,0.f,0.f,0.f};
    f32x4 acc2[4][4];
    #pragma unroll
    for (int m=0;m<4;m++)
        #pragma unroll
        for (int f=0;f<4;f++) acc2[m][f] = zero4;

    for (int hc = 0; hc < 1024; hc += 128) {
        int hbase = hc + w*32;
        f32x4 c1[2][4];
        #pragma unroll
        for (int m=0;m<2;m++)
            #pragma unroll
            for (int f=0;f<4;f++) c1[m][f] = zero4;
        for (int ks = 0; ks < 8; ks++) {
            bf16x8 afr[2];
            #pragma unroll
            for (int m=0;m<2;m++)
                afr[m] = *(const bf16x8*)&w1bf[(size_t)(hbase + m*16 + (lane&15))*256
                                               + ks*32 + (lane>>4)*8];
            #pragma unroll
            for (int f=0;f<4;f++){
                int px = f*16 + (lane&15);
                int g = (ks*4 + (lane>>4)) ^ (px&7);
                bf16x8 bfr = *(const bf16x8*)&Xs[px*256 + g*8];
                #pragma unroll
                for (int m=0;m<2;m++)
                    c1[m][f] = __builtin_amdgcn_mfma_f32_16x16x32_bf16(afr[m], bfr, c1[m][f], 0,0,0);
            }
        }
        __syncthreads();   // prev GEMM2 readers of Ts done
        #pragma unroll
        for (int m=0;m<2;m++){
            #pragma unroll
            for (int r=0;r<4;r++){
                int h = hbase + m*16 + (lane>>4)*4 + r;
                float s1 = sc1[h], bb1 = sb1[h];
                int hl = h - hc;
                #pragma unroll
                for (int f=0;f<4;f++){
                    int px = f*16 + (lane&15);
                    float t = fmaxf(c1[m][f][r]*s1 + bb1, 0.f);
                    int g = (hl>>3) ^ (px&7);
                    Ts[px*128 + g*8 + (hl&7)] = f2b(t);
                }
            }
        }
        __syncthreads();
        int c0 = w*64;
        for (int ks = 0; ks < 4; ks++) {
            bf16x8 afr[4];
            #pragma unroll
            for (int m=0;m<4;m++)
                afr[m] = *(const bf16x8*)&w2bf[(size_t)(c0 + m*16 + (lane&15))*1024
                                               + hc + ks*32 + (lane>>4)*8];
            #pragma unroll
            for (int f=0;f<4;f++){
                int px = f*16 + (lane&15);
                int hl = ks*32 + (lane>>4)*8;
                int g = (hl>>3) ^ (px&7);
                bf16x8 bfr = *(const bf16x8*)&Ts[px*128 + g*8];
                #pragma unroll
                for (int m=0;m<4;m++)
                    acc2[m][f] = __builtin_amdgcn_mfma_f32_16x16x32_bf16(afr[m], bfr, acc2[m][f], 0,0,0);
            }
        }
    }

    float* op = out + (size_t)b*256*4096 + l0;
    int c0 = w*64;
    #pragma unroll
    for (int m=0;m<4;m++){
        #pragma unroll
        for (int r=0;r<4;r++){
            int c = c0 + m*16 + (lane>>4)*4 + r;
            float a = sigm(alpha[768+c]);
            float s2 = sc2[c], bb2 = sb2[c];
            #pragma unroll
            for (int f=0;f<4;f++){
                int px = f*16 + (lane&15);
                float t2 = acc2[m][f][r]*s2 + bb2;
                float xv = LD(&xp[(size_t)c*4096 + px]);
                op[(size_t)c*4096 + px] = (1.f-a)*xv + a*t2;
            }
        }
    }
}

// ---------- pipeline (templated on residual-stream storage type) ----------
template<typename TX>
static void run_all(const float* x, TX* x1, float* d_out_x, float* hout_out,
                    const float* dw1w, const float* dw1g, const float* dw1b,
                    const float* dw1m, const float* dw1v,
                    const float* lnw, const float* lnb,
                    const ushort* wbc, const float* dwmw, const float* Ap,
                    const float* hzw, const float* outw, const float* Dp,
                    const float* dw2w, const float* dw2g, const float* dw2b,
                    const float* dw2m, const float* dw2v,
                    const ushort* w1bf, const ushort* w2bf,
                    const float* sc1, const float* sb1,
                    const float* sc2, const float* sb2,
                    const float* alpha,
                    float* meanp, float* invp, char* cbase, int NB,
                    hipStream_t stream)
{
    bf16*   bc      = (bf16*)cbase;
    ushort* xn_bf   = (ushort*)(cbase + (size_t)NB*1572864);
    float*  h_part  = (float*)(cbase + (size_t)NB*(1572864 + 2097152));
    float*  hg      = (float*)((char*)h_part + (size_t)NB*524288);
    ushort* hout_bf = (ushort*)((char*)hg + (size_t)NB*65536);

    dwconv_bn_blend<float,TX><<<8192,256,0,stream>>>(x, x1, dw1w,dw1g,dw1b,dw1m,dw1v, alpha, 0);
    if constexpr (std::is_same<TX,bf16>::value)
        ln_stats_bf<<<256,256,0,stream>>>(x1, meanp, invp);
    else
        ln_stats_f<<<512,256,0,stream>>>((const float*)x1, meanp, invp);

    for (int b0 = 0; b0 < 32; b0 += NB) {
        bcdt_mfma<TX><<<NB*64,256,0,stream>>>(x1, meanp, invp, lnw, lnb, wbc, bc, xn_bf, b0);
        dwconv_plain<<<NB*192,256,0,stream>>>(bc, dwmw);
        softmax_ab<<<NB*64,256,0,stream>>>(bc, Ap);
        h_mfma<<<NB*8,256,0,stream>>>(xn_bf, bc, h_part);
        hz_gate<<<NB*4,256,0,stream>>>(h_part, hzw, Dp, hg);
        out_gemm<<<NB*4,256,0,stream>>>(hg, outw, hout_bf, hout_out, b0);
        y_mfma<TX><<<NB*64,256,0,stream>>>(hout_bf, bc, x1, alpha, b0);
    }

    dwconv_bn_blend<TX,TX><<<8192,256,0,stream>>>(x1, x1, dw2w,dw2g,dw2b,dw2m,dw2v, alpha, 2);
    ffn_mfma<TX><<<2048,256,0,stream>>>(x1, w1bf, w2bf, sc1, sb1, sc2, sb2, alpha, d_out_x);
}

extern "C" void kernel_launch(void* const* d_in, const int* in_sizes, int n_in,
                              void* d_out, int out_size, void* d_ws, size_t ws_size,
                              hipStream_t stream)
{
    (void)in_sizes; (void)n_in; (void)out_size;
    const float* x     = (const float*)d_in[0];
    const float* dw1w  = (const float*)d_in[1];
    const float* dw1g  = (const float*)d_in[2];
    const float* dw1b  = (const float*)d_in[3];
    const float* dw1m  = (const float*)d_in[4];
    const float* dw1v  = (const float*)d_in[5];
    const float* lnw   = (const float*)d_in[6];
    const float* lnb   = (const float*)d_in[7];
    const float* bcdtw = (const float*)d_in[8];
    const float* dwmw  = (const float*)d_in[9];
    const float* Ap    = (const float*)d_in[10];
    const float* hzw   = (const float*)d_in[11];
    const float* outw  = (const float*)d_in[12];
    const float* Dp    = (const float*)d_in[13];
    const float* dw2w  = (const float*)d_in[14];
    const float* dw2g  = (const float*)d_in[15];
    const float* dw2b  = (const float*)d_in[16];
    const float* dw2m  = (const float*)d_in[17];
    const float* dw2v  = (const float*)d_in[18];
    const float* f1w   = (const float*)d_in[19];
    const float* f1g   = (const float*)d_in[20];
    const float* f1b   = (const float*)d_in[21];
    const float* f1m   = (const float*)d_in[22];
    const float* f1v   = (const float*)d_in[23];
    const float* f2w   = (const float*)d_in[24];
    const float* f2g   = (const float*)d_in[25];
    const float* f2b_  = (const float*)d_in[26];
    const float* f2m   = (const float*)d_in[27];
    const float* f2v   = (const float*)d_in[28];
    const float* alpha = (const float*)d_in[29];

    const size_t nx = (size_t)32*256*4096;
    float* d_out_x  = (float*)d_out;
    float* hout_out = d_out_x + nx;

    char* ws = (char*)d_ws;
    float* meanp = (float*)ws;                       // 512 KB
    float* invp  = meanp + 131072;                   // 512 KB
    size_t off = 1048576;
    ushort* w1bf = (ushort*)(ws + off); off += 524288;
    ushort* w2bf = (ushort*)(ws + off); off += 524288;
    ushort* wbc  = (ushort*)(ws + off); off += 98304;
    float* sc1 = (float*)(ws + off); off += 4096;
    float* sb1 = (float*)(ws + off); off += 4096;
    float* sc2 = (float*)(ws + off); off += 1024;
    float* sb2 = (float*)(ws + off); off += 1024;
    off = (off + 255) & ~(size_t)255;

    // per-b: bc 1.5M + xn_bf 2M + h_part 512K + hg 64K + hout_bf 32K
    const size_t perb = 1572864 + 2097152 + 524288 + 65536 + 32768; // 4,292,608
    size_t avail = ws_size > off ? ws_size - off : 0;

    prep_k<<<1024,256,0,stream>>>(f1w, f2w, bcdtw, f1g,f1b,f1m,f1v, f2g,f2b_,f2m,f2v,
                                  w1bf, w2bf, wbc, sc1, sb1, sc2, sb2);

    // Prefer bf16 residual stream (halves x1 traffic) when ws fits x1_bf + NB>=8 chunks.
    if (avail >= nx*2 + 8*perb) {
        bf16* x1b = (bf16*)(ws + off); off += nx*2;
        char* cbase = ws + off;
        size_t a2 = ws_size - off;
        int NB = 8;
        for (int nb = 32; nb >= 8; nb >>= 1) if (a2 >= (size_t)nb*perb) { NB = nb; break; }
        run_all<bf16>(x, x1b, d_out_x, hout_out,
                      dw1w,dw1g,dw1b,dw1m,dw1v, lnw,lnb, wbc, dwmw, Ap, hzw, outw, Dp,
                      dw2w,dw2g,dw2b,dw2m,dw2v, w1bf,w2bf, sc1,sb1,sc2,sb2, alpha,
                      meanp, invp, cbase, NB, stream);
    } else {
        char* cbase = ws + off;
        int NB = 1;
        for (int nb = 32; nb >= 1; nb >>= 1) if (avail >= (size_t)nb*perb) { NB = nb; break; }
        run_all<float>(x, d_out_x, d_out_x, hout_out,
                       dw1w,dw1g,dw1b,dw1m,dw1v, lnw,lnb, wbc, dwmw, Ap, hzw, outw, Dp,
                       dw2w,dw2g,dw2b,dw2m,dw2v, w1bf,w2bf, sc1,sb1,sc2,sb2, alpha,
                       meanp, invp, cbase, NB, stream);
    }
}